// Round 1
// baseline (5053.514 us; speedup 1.0000x reference)
//
#include <hip/hip_runtime.h>
#include <stdint.h>

#define DD 256
#define NEDGE 300000
#define NNODE 100000
#define NLAY 9
#define LN_EPS 1e-5f

typedef __attribute__((ext_vector_type(8))) short bf16x8;
typedef __attribute__((ext_vector_type(4))) short s16x4;
typedef __attribute__((ext_vector_type(4))) float f32x4;
typedef __attribute__((ext_vector_type(4))) int i32x4;

static __device__ __forceinline__ short f2bf(float f) {
  union { float f; uint32_t u; } v; v.f = f;
  uint32_t r = (v.u + 0x7FFFu + ((v.u >> 16) & 1u)) >> 16;
  return (short)(uint16_t)r;
}
static __device__ __forceinline__ float bf2f(short s) {
  union { uint32_t u; float f; } v; v.u = ((uint32_t)(uint16_t)s) << 16;
  return v.f;
}

// ---------------------------------------------------------------------------
// Fused MLP: out = LN(relu(A @ W1^T + b1) @ W2^T + b2) * g + b  [+ resid]
// Block: 256 thr = 4 waves (2M x 2N), BM=64 rows, N=256, K=256 (8 steps of 32)
// ---------------------------------------------------------------------------
template<bool A_F32, bool NODE>
__global__ __launch_bounds__(256, 2) void mlp_kernel(
    const void* __restrict__ Ain, const short* __restrict__ W1,
    const short* __restrict__ W2, const float* __restrict__ B1,
    const float* __restrict__ B2, const float* __restrict__ LG,
    const float* __restrict__ LB, void* __restrict__ Outp,
    const float* __restrict__ Resid, int M) {
  extern __shared__ char smem[];
  short* wbuf = (short*)smem;              // [4][256][8] bf16 (16KB)
  short* hidden = (short*)(smem + 16384);  // [64][256] bf16, granule-swizzled (32KB)
  const int tid = threadIdx.x;
  const int lane = tid & 63;
  const int wv = tid >> 6;
  const int wm = wv >> 1, wn = wv & 1;
  const int l15 = lane & 15, lq = lane >> 4;
  const int r0 = blockIdx.x * 64;

  const f32x4 vzero = {0.f, 0.f, 0.f, 0.f};
  f32x4 acc[2][8];
#pragma unroll
  for (int mi = 0; mi < 2; ++mi)
#pragma unroll
    for (int ni = 0; ni < 8; ++ni) acc[mi][ni] = vzero;

  const int arow0 = min(r0 + wm * 32 + l15, M - 1);
  const int arow1 = min(r0 + wm * 32 + 16 + l15, M - 1);

  // ------------------------- GEMM1: h = relu(A @ W1^T + b1) ----------------
  for (int kk = 0; kk < 8; ++kk) {
#pragma unroll
    for (int i = 0; i < 4; ++i) {
      const int idx = tid + 256 * i;
      const int q = idx >> 8, o = idx & 255;
      const i32x4 w = *(const i32x4*)(W1 + o * DD + kk * 32 + q * 8);
      *(i32x4*)(wbuf + q * 2048 + o * 8) = w;
    }
    bf16x8 a0, a1;
    if (A_F32) {
      const float* A = (const float*)Ain;
      const f32x4 u0 = *(const f32x4*)(A + arow0 * DD + kk * 32 + lq * 8);
      const f32x4 u1 = *(const f32x4*)(A + arow0 * DD + kk * 32 + lq * 8 + 4);
      const f32x4 u2 = *(const f32x4*)(A + arow1 * DD + kk * 32 + lq * 8);
      const f32x4 u3 = *(const f32x4*)(A + arow1 * DD + kk * 32 + lq * 8 + 4);
#pragma unroll
      for (int j = 0; j < 4; ++j) {
        a0[j] = f2bf(u0[j]); a0[j + 4] = f2bf(u1[j]);
        a1[j] = f2bf(u2[j]); a1[j + 4] = f2bf(u3[j]);
      }
    } else {
      const short* A = (const short*)Ain;
      a0 = *(const bf16x8*)(A + arow0 * DD + kk * 32 + lq * 8);
      a1 = *(const bf16x8*)(A + arow1 * DD + kk * 32 + lq * 8);
    }
    __syncthreads();
#pragma unroll
    for (int ni = 0; ni < 8; ++ni) {
      const bf16x8 b = *(const bf16x8*)(wbuf + lq * 2048 + (wn * 128 + ni * 16 + l15) * 8);
      acc[0][ni] = __builtin_amdgcn_mfma_f32_16x16x32_bf16(a0, b, acc[0][ni], 0, 0, 0);
      acc[1][ni] = __builtin_amdgcn_mfma_f32_16x16x32_bf16(a1, b, acc[1][ni], 0, 0, 0);
    }
    __syncthreads();
  }
  // epilogue 1: bias + relu -> hidden (swizzled bf16)
#pragma unroll
  for (int ni = 0; ni < 8; ++ni) {
    const int c = wn * 128 + ni * 16 + l15;
    const float bb = B1[c];
#pragma unroll
    for (int mi = 0; mi < 2; ++mi)
#pragma unroll
      for (int i = 0; i < 4; ++i) {
        const int row = wm * 32 + mi * 16 + lq * 4 + i;
        const float v = fmaxf(acc[mi][ni][i] + bb, 0.f);
        hidden[row * DD + ((((c >> 3) ^ (row & 7))) << 3) + (c & 7)] = f2bf(v);
        acc[mi][ni][i] = 0.f;
      }
  }
  __syncthreads();
  // ------------------------- GEMM2: y = h @ W2^T ---------------------------
  for (int kk = 0; kk < 8; ++kk) {
#pragma unroll
    for (int i = 0; i < 4; ++i) {
      const int idx = tid + 256 * i;
      const int q = idx >> 8, o = idx & 255;
      const i32x4 w = *(const i32x4*)(W2 + o * DD + kk * 32 + q * 8);
      *(i32x4*)(wbuf + q * 2048 + o * 8) = w;
    }
    __syncthreads();
    const int hr0 = wm * 32 + l15;
    const int hr1 = hr0 + 16;
    const bf16x8 a0 = *(const bf16x8*)(hidden + hr0 * DD + (((kk * 4 + lq) ^ (hr0 & 7)) << 3));
    const bf16x8 a1 = *(const bf16x8*)(hidden + hr1 * DD + (((kk * 4 + lq) ^ (hr1 & 7)) << 3));
#pragma unroll
    for (int ni = 0; ni < 8; ++ni) {
      const bf16x8 b = *(const bf16x8*)(wbuf + lq * 2048 + (wn * 128 + ni * 16 + l15) * 8);
      acc[0][ni] = __builtin_amdgcn_mfma_f32_16x16x32_bf16(a0, b, acc[0][ni], 0, 0, 0);
      acc[1][ni] = __builtin_amdgcn_mfma_f32_16x16x32_bf16(a1, b, acc[1][ni], 0, 0, 0);
    }
    __syncthreads();
  }
  // epilogue 2: bias + LayerNorm (+resid)
  float b2v[8], gv[8], bv[8];
#pragma unroll
  for (int ni = 0; ni < 8; ++ni) {
    const int c = wn * 128 + ni * 16 + l15;
    b2v[ni] = B2[c]; gv[ni] = LG[c]; bv[ni] = LB[c];
  }
  float mean_[2][4], inv_[2][4];
#pragma unroll
  for (int mi = 0; mi < 2; ++mi)
#pragma unroll
    for (int i = 0; i < 4; ++i) {
      float s1 = 0.f, s2 = 0.f;
#pragma unroll
      for (int ni = 0; ni < 8; ++ni) {
        const float v = acc[mi][ni][i] + b2v[ni];
        s1 += v; s2 += v * v;
      }
#pragma unroll
      for (int off = 1; off < 16; off <<= 1) {
        s1 += __shfl_xor(s1, off);
        s2 += __shfl_xor(s2, off);
      }
      mean_[mi][i] = s1; inv_[mi][i] = s2;  // stash partial totals
    }
  float* redbuf = (float*)smem;  // [64][2 halves][2]
  if (l15 == 0) {
#pragma unroll
    for (int mi = 0; mi < 2; ++mi)
#pragma unroll
      for (int i = 0; i < 4; ++i) {
        const int row = wm * 32 + mi * 16 + lq * 4 + i;
        redbuf[row * 4 + wn * 2 + 0] = mean_[mi][i];
        redbuf[row * 4 + wn * 2 + 1] = inv_[mi][i];
      }
  }
  __syncthreads();
#pragma unroll
  for (int mi = 0; mi < 2; ++mi)
#pragma unroll
    for (int i = 0; i < 4; ++i) {
      const int row = wm * 32 + mi * 16 + lq * 4 + i;
      const float t1 = redbuf[row * 4 + 0] + redbuf[row * 4 + 2];
      const float t2 = redbuf[row * 4 + 1] + redbuf[row * 4 + 3];
      const float mean = t1 * (1.f / 256.f);
      const float var = t2 * (1.f / 256.f) - mean * mean;
      mean_[mi][i] = mean;
      inv_[mi][i] = rsqrtf(var + LN_EPS);
    }
  __syncthreads();  // redbuf consumed; safe to overwrite smem

  if (NODE) {
    float* ob = (float*)smem;  // [64][256] f32, granule-swizzled (64KB)
#pragma unroll
    for (int ni = 0; ni < 8; ++ni) {
      const int c = wn * 128 + ni * 16 + l15;
#pragma unroll
      for (int mi = 0; mi < 2; ++mi)
#pragma unroll
        for (int i = 0; i < 4; ++i) {
          const int row = wm * 32 + mi * 16 + lq * 4 + i;
          const float v = acc[mi][ni][i] + b2v[ni];
          const float y = (v - mean_[mi][i]) * inv_[mi][i] * gv[ni] + bv[ni];
          ob[row * DD + (((c >> 2) ^ (row & 7)) << 2) + (c & 3)] = y;
        }
    }
    __syncthreads();
    float* Out = (float*)Outp;
#pragma unroll
    for (int j = 0; j < 16; ++j) {
      const int gg = tid + 256 * j;
      const int row = gg >> 6, Lg = gg & 63;
      const int grow = r0 + row;
      if (grow < M) {
        f32x4 v = *(const f32x4*)(ob + row * DD + ((Lg ^ (row & 7)) << 2));
        const f32x4 xr = *(const f32x4*)(Resid + (size_t)grow * DD + Lg * 4);
        v = v + xr;
        *(f32x4*)(Out + (size_t)grow * DD + Lg * 4) = v;
      }
    }
  } else {
    short* ob = hidden;  // reuse hidden region, same swizzle
#pragma unroll
    for (int ni = 0; ni < 8; ++ni) {
      const int c = wn * 128 + ni * 16 + l15;
#pragma unroll
      for (int mi = 0; mi < 2; ++mi)
#pragma unroll
        for (int i = 0; i < 4; ++i) {
          const int row = wm * 32 + mi * 16 + lq * 4 + i;
          const float v = acc[mi][ni][i] + b2v[ni];
          const float y = (v - mean_[mi][i]) * inv_[mi][i] * gv[ni] + bv[ni];
          ob[row * DD + (((c >> 3) ^ (row & 7)) << 3) + (c & 7)] = f2bf(y);
        }
    }
    __syncthreads();
    short* Out = (short*)Outp;
#pragma unroll
    for (int j = 0; j < 8; ++j) {
      const int gg = tid + 256 * j;
      const int row = gg >> 5, Lg = gg & 31;
      const int grow = r0 + row;
      if (grow < M) {
        const i32x4 v = *(const i32x4*)(ob + row * DD + ((Lg ^ (row & 7)) << 3));
        *(i32x4*)(Out + (size_t)grow * DD + Lg * 8) = v;
      }
    }
  }
}

// ----------------------- aggregation via CSR (no atomics in hot path) ------
__global__ __launch_bounds__(256) void aggregate_kernel(
    const float* __restrict__ x, const short* __restrict__ efeat,
    const int* __restrict__ offs, const int* __restrict__ seid,
    const int* __restrict__ ssrc, short* __restrict__ aggr) {
  const int n = blockIdx.x;
  const int d = threadIdx.x;
  const int beg = offs[n], end = offs[n + 1];
  float v = 0.f;
  for (int p = beg; p < end; ++p) {
    const int e = seid[p];
    const int s = ssrc[p];
    v += x[(size_t)s * DD + d] + bf2f(efeat[(size_t)e * DD + d]);
  }
  aggr[(size_t)n * DD + d] = f2bf(v);
}

__global__ void count_kernel(const int* __restrict__ tgt, int* __restrict__ deg) {
  const int e = blockIdx.x * 256 + threadIdx.x;
  if (e < NEDGE) atomicAdd(&deg[tgt[e]], 1);
}

__global__ __launch_bounds__(1024) void scan_kernel(
    const int* __restrict__ deg, int* __restrict__ offs, int* __restrict__ cur) {
  __shared__ int part[1024];
  const int t = threadIdx.x;
  const int CH = 98;  // 1024*98 >= 100000
  const int base = t * CH;
  int s = 0;
  for (int i = 0; i < CH; ++i) {
    const int idx = base + i;
    if (idx < NNODE) s += deg[idx];
  }
  part[t] = s;
  __syncthreads();
  for (int off = 1; off < 1024; off <<= 1) {
    const int v = (t >= off) ? part[t - off] : 0;
    __syncthreads();
    part[t] += v;
    __syncthreads();
  }
  int run = (t > 0) ? part[t - 1] : 0;  // exclusive prefix
  for (int i = 0; i < CH; ++i) {
    const int idx = base + i;
    if (idx < NNODE) {
      offs[idx] = run;
      cur[idx] = run;
      run += deg[idx];
    }
  }
  if (t == 1023) offs[NNODE] = part[1023];
}

__global__ void fill_kernel(const int* __restrict__ src, const int* __restrict__ tgt,
                            int* cur, int* seid, int* ssrc) {
  const int e = blockIdx.x * 256 + threadIdx.x;
  if (e < NEDGE) {
    const int t = tgt[e];
    const int p = atomicAdd(&cur[t], 1);
    seid[p] = e;
    ssrc[p] = src[e];
  }
}

__global__ void cvt4_kernel(const float* __restrict__ src, short* __restrict__ dst, int n4) {
  for (int i = blockIdx.x * blockDim.x + threadIdx.x; i < n4; i += gridDim.x * blockDim.x) {
    const f32x4 v = ((const f32x4*)src)[i];
    s16x4 o;
    o.x = f2bf(v.x); o.y = f2bf(v.y); o.z = f2bf(v.z); o.w = f2bf(v.w);
    ((s16x4*)dst)[i] = o;
  }
}

// ---------------------------------------------------------------------------
extern "C" void kernel_launch(void* const* d_in, const int* in_sizes, int n_in,
                              void* d_out, int out_size, void* d_ws, size_t ws_size,
                              hipStream_t stream) {
  const float* x_in = (const float*)d_in[0];
  const float* ea_f = (const float*)d_in[1];
  const float* e1w = (const float*)d_in[2];
  const float* e1b = (const float*)d_in[3];
  const float* e2w = (const float*)d_in[4];
  const float* e2b = (const float*)d_in[5];
  const float* elg = (const float*)d_in[6];
  const float* elb = (const float*)d_in[7];
  const float* n1w = (const float*)d_in[8];
  const float* n1b = (const float*)d_in[9];
  const float* n2w = (const float*)d_in[10];
  const float* n2b = (const float*)d_in[11];
  const float* nlg = (const float*)d_in[12];
  const float* nlb = (const float*)d_in[13];
  const int* eidx = (const int*)d_in[14];
  float* x = (float*)d_out;

  char* p = (char*)d_ws;
  auto take = [&](size_t bytes) {
    char* r = p;
    p += (bytes + 255) & ~(size_t)255;
    return r;
  };
  short* efeat = (short*)take((size_t)NEDGE * DD * 2);
  short* aggr = (short*)take((size_t)NNODE * DD * 2);
  short* we1 = (short*)take((size_t)NLAY * DD * DD * 2);
  short* we2 = (short*)take((size_t)NLAY * DD * DD * 2);
  short* wn1 = (short*)take((size_t)NLAY * DD * DD * 2);
  short* wn2 = (short*)take((size_t)NLAY * DD * DD * 2);
  int* deg = (int*)take((size_t)NNODE * 4);
  int* offs = (int*)take((size_t)(NNODE + 1) * 4);
  int* cur = (int*)take((size_t)NNODE * 4);
  int* seid = (int*)take((size_t)NEDGE * 4);
  int* ssrc = (int*)take((size_t)NEDGE * 4);
  short* eab = (short*)take((size_t)NEDGE * DD * 2);
  const bool use_eab = ((size_t)(p - (char*)d_ws) <= ws_size);

  hipMemcpyAsync(x, x_in, (size_t)NNODE * DD * 4, hipMemcpyDeviceToDevice, stream);

  const int wn4 = NLAY * DD * DD / 4;
  cvt4_kernel<<<576, 256, 0, stream>>>(e1w, we1, wn4);
  cvt4_kernel<<<576, 256, 0, stream>>>(e2w, we2, wn4);
  cvt4_kernel<<<576, 256, 0, stream>>>(n1w, wn1, wn4);
  cvt4_kernel<<<576, 256, 0, stream>>>(n2w, wn2, wn4);
  if (use_eab) cvt4_kernel<<<2048, 256, 0, stream>>>(ea_f, eab, NEDGE * DD / 4);

  hipMemsetAsync(deg, 0, (size_t)NNODE * 4, stream);
  count_kernel<<<(NEDGE + 255) / 256, 256, 0, stream>>>(eidx + NEDGE, deg);
  scan_kernel<<<1, 1024, 0, stream>>>(deg, offs, cur);
  fill_kernel<<<(NEDGE + 255) / 256, 256, 0, stream>>>(eidx, eidx + NEDGE, cur, seid, ssrc);

  const int egrid = (NEDGE + 63) / 64;
  const int ngrid = (NNODE + 63) / 64;
  for (int l = 0; l < NLAY; ++l) {
    if (use_eab) {
      mlp_kernel<false, false><<<egrid, 256, 49152, stream>>>(
          eab, we1 + l * DD * DD, we2 + l * DD * DD, e1b + l * DD, e2b + l * DD,
          elg + l * DD, elb + l * DD, efeat, nullptr, NEDGE);
    } else {
      mlp_kernel<true, false><<<egrid, 256, 49152, stream>>>(
          ea_f, we1 + l * DD * DD, we2 + l * DD * DD, e1b + l * DD, e2b + l * DD,
          elg + l * DD, elb + l * DD, efeat, nullptr, NEDGE);
    }
    aggregate_kernel<<<NNODE, 256, 0, stream>>>(x, efeat, offs, seid, ssrc, aggr);
    mlp_kernel<false, true><<<ngrid, 256, 65536, stream>>>(
        aggr, wn1 + l * DD * DD, wn2 + l * DD * DD, n1b + l * DD, n2b + l * DD,
        nlg + l * DD, nlb + l * DD, x, x, NNODE);
  }
  (void)in_sizes; (void)n_in; (void)out_size; (void)ws_size;
}